// Round 4
// baseline (3636.686 us; speedup 1.0000x reference)
//
#include <hip/hip_runtime.h>

#define NTOK 49
#define HEADS 8
#define HDIM 32
#define DIM 256
#define NW 64
#define NBLK 4096

#define XS_STRIDE 260   // floats, row = 1040 B (16B aligned)
#define QK_STRIDE 772   // ushorts, row = 1544 B (8B aligned)

struct Smem {
  float xs[NTOK][XS_STRIDE];             // x, later attention output (fp32)
  unsigned short qkvs[NTOK][QK_STRIDE];  // q|k|v bf16, col = qkv*256 + h*32 + d
  float rel[169 * 8];
  float mls[NTOK * NTOK];
};                                        // 141628 B static

__device__ __forceinline__ unsigned short f2bf(float f) {
  unsigned u = __float_as_uint(f);
  return (unsigned short)((u + 0x7fffu + ((u >> 16) & 1u)) >> 16);
}
__device__ __forceinline__ unsigned packbf(float a, float b) {
  return (unsigned)f2bf(a) | ((unsigned)f2bf(b) << 16);
}
__device__ __forceinline__ float bflo(unsigned u) { return __uint_as_float(u << 16); }
__device__ __forceinline__ float bfhi(unsigned u) { return __uint_as_float(u & 0xffff0000u); }

__global__ void __launch_bounds__(512) winattn_kernel(
    const float* __restrict__ x,
    const float* __restrict__ mask,
    const float* __restrict__ w_qkv,
    const float* __restrict__ b_qkv,
    const float* __restrict__ rel_table,
    const float* __restrict__ w_out,
    const float* __restrict__ b_out,
    float* __restrict__ out)
{
  __shared__ Smem sm;

  const int b    = blockIdx.x;
  const int tid  = threadIdx.x;
  const int lane = tid & 63;
  const int g    = tid >> 6;   // wave id 0..7

  // ---------------- stage x, rel_table, mask (fp32 global -> LDS) ----------------
  {
    const float4* xg = (const float4*)(x + (size_t)b * (NTOK * DIM));
    for (int e = tid; e < NTOK * DIM / 4; e += 512) {
      int row = e >> 6;
      int col = (e & 63) << 2;
      *(float4*)&sm.xs[row][col] = xg[e];
    }
    const float2* rg = (const float2*)rel_table;
    for (int e = tid; e < 169 * 8 / 2; e += 512) {
      *(float2*)&sm.rel[e * 2] = rg[e];
    }
    const float* mrow = mask + (size_t)(b & (NW - 1)) * (NTOK * NTOK);
    for (int e = tid; e < NTOK * NTOK; e += 512) sm.mls[e] = mrow[e];
  }
  __syncthreads();

  // ---------------- QKV GEMM: (49x256)@(256x768)+b -> bf16 LDS ----------------
  if (g < 7) {
    const int r0 = g * 7;
    for (int pass = 0; pass < 3; ++pass) {
      const int c0 = pass * 256 + lane * 4;
      float acc[7][4];
      {
        float4 bv = *(const float4*)(b_qkv + c0);
        #pragma unroll
        for (int r = 0; r < 7; ++r) {
          acc[r][0] = bv.x; acc[r][1] = bv.y; acc[r][2] = bv.z; acc[r][3] = bv.w;
        }
      }
      #pragma unroll 4
      for (int k = 0; k < DIM; ++k) {
        float4 wv = *(const float4*)(w_qkv + (size_t)k * 768 + c0);
        float xv[7];
        #pragma unroll
        for (int r = 0; r < 7; ++r) xv[r] = sm.xs[r0 + r][k];
        #pragma unroll
        for (int r = 0; r < 7; ++r) {
          acc[r][0] = fmaf(xv[r], wv.x, acc[r][0]);
          acc[r][1] = fmaf(xv[r], wv.y, acc[r][1]);
          acc[r][2] = fmaf(xv[r], wv.z, acc[r][2]);
          acc[r][3] = fmaf(xv[r], wv.w, acc[r][3]);
        }
      }
      #pragma unroll
      for (int r = 0; r < 7; ++r) {
        uint2 st;
        st.x = packbf(acc[r][0], acc[r][1]);
        st.y = packbf(acc[r][2], acc[r][3]);
        *(uint2*)&sm.qkvs[r0 + r][c0] = st;
      }
    }
  }
  __syncthreads();

  // ---------------- attention: wave = head h, lane = row i ----------------
  // a[i,j] = k_i . q_j / sqrt(32) + bias[h,i,j] + mask[i,j]; softmax over j; y_i = sum_j p_j v_j
  {
    const int h = g;
    const int i = lane;
    if (i < NTOK) {
      const int qoff = h * HDIM;
      float kr[32];
      #pragma unroll
      for (int dp = 0; dp < 16; ++dp) {
        unsigned u = *(const unsigned*)&sm.qkvs[i][256 + qoff + dp * 2];
        kr[dp * 2] = bflo(u); kr[dp * 2 + 1] = bfhi(u);
      }
      const int ih = i / 7, iw = i - ih * 7;
      float s[NTOK];
      float m = -1e30f;
      #pragma unroll
      for (int j = 0; j < NTOK; ++j) {
        float acc = 0.f;
        #pragma unroll
        for (int dp = 0; dp < 16; ++dp) {
          unsigned u = *(const unsigned*)&sm.qkvs[j][qoff + dp * 2];
          acc = fmaf(kr[dp * 2], bflo(u), acc);
          acc = fmaf(kr[dp * 2 + 1], bfhi(u), acc);
        }
        const int jh = j / 7, jw = j - jh * 7;
        float bias = sm.rel[((ih - jh + 6) * 13 + (iw - jw + 6)) * 8 + h];
        acc = fmaf(acc, 0.17677669529663687f, bias + sm.mls[i * 49 + j]);
        s[j] = acc;
        m = fmaxf(m, acc);
      }
      float y[32];
      #pragma unroll
      for (int d = 0; d < 32; ++d) y[d] = 0.f;
      float sum = 0.f;
      #pragma unroll
      for (int j = 0; j < NTOK; ++j) {
        float p = __expf(s[j] - m);
        sum += p;
        #pragma unroll
        for (int dp = 0; dp < 16; ++dp) {
          unsigned u = *(const unsigned*)&sm.qkvs[j][512 + qoff + dp * 2];
          y[dp * 2]     = fmaf(p, bflo(u), y[dp * 2]);
          y[dp * 2 + 1] = fmaf(p, bfhi(u), y[dp * 2 + 1]);
        }
      }
      float inv = 1.f / sum;
      #pragma unroll
      for (int dp = 0; dp < 16; ++dp) {
        *(float2*)&sm.xs[i][qoff + dp * 2] =
            make_float2(y[dp * 2] * inv, y[dp * 2 + 1] * inv);
      }
    }
  }
  __syncthreads();

  // ---------------- output proj: (49x256)@(256x256)+b -> FP32 global ----------------
  if (g < 7) {
    const int r0 = g * 7;
    const int c0 = lane * 4;
    float acc[7][4];
    {
      float4 bv = *(const float4*)(b_out + c0);
      #pragma unroll
      for (int r = 0; r < 7; ++r) {
        acc[r][0] = bv.x; acc[r][1] = bv.y; acc[r][2] = bv.z; acc[r][3] = bv.w;
      }
    }
    #pragma unroll 4
    for (int k = 0; k < DIM; ++k) {
      float4 wv = *(const float4*)(w_out + (size_t)k * 256 + c0);
      float xv[7];
      #pragma unroll
      for (int r = 0; r < 7; ++r) xv[r] = sm.xs[r0 + r][k];
      #pragma unroll
      for (int r = 0; r < 7; ++r) {
        acc[r][0] = fmaf(xv[r], wv.x, acc[r][0]);
        acc[r][1] = fmaf(xv[r], wv.y, acc[r][1]);
        acc[r][2] = fmaf(xv[r], wv.z, acc[r][2]);
        acc[r][3] = fmaf(xv[r], wv.w, acc[r][3]);
      }
    }
    float* ob = out + (size_t)b * NTOK * DIM;
    #pragma unroll
    for (int r = 0; r < 7; ++r) {
      float4 st = make_float4(acc[r][0], acc[r][1], acc[r][2], acc[r][3]);
      *(float4*)(ob + (r0 + r) * DIM + c0) = st;
    }
  }
}

extern "C" void kernel_launch(void* const* d_in, const int* in_sizes, int n_in,
                              void* d_out, int out_size, void* d_ws, size_t ws_size,
                              hipStream_t stream) {
  // Bind inputs by element count (all 7 sizes are distinct).
  const float *x = nullptr, *mask = nullptr, *w_qkv = nullptr, *b_qkv = nullptr,
              *rel_t = nullptr, *w_out = nullptr, *b_out = nullptr;
  for (int i = 0; i < n_in; ++i) {
    const float* p = (const float*)d_in[i];
    switch (in_sizes[i]) {
      case 4096 * 49 * 256: x = p; break;       // 51380224
      case 64 * 49 * 49:    mask = p; break;    // 153664
      case 256 * 768:       w_qkv = p; break;   // 196608
      case 768:             b_qkv = p; break;
      case 169 * 8:         rel_t = p; break;   // 1352
      case 256 * 256:       w_out = p; break;   // 65536
      case 256:             b_out = p; break;
    }
  }
  float* out = (float*)d_out;

  hipLaunchKernelGGL(winattn_kernel, dim3(NBLK), dim3(512), 0, stream,
                     x, mask, w_qkv, b_qkv, rel_t, w_out, b_out, out);
}

// Round 5
// 494.523 us; speedup vs baseline: 7.3539x; 7.3539x over previous
//
#include <hip/hip_runtime.h>

typedef __attribute__((ext_vector_type(8))) short short8;
typedef __attribute__((ext_vector_type(4))) float f32x4;

#define NTOK 49
#define DIM 256
#define NBLK 4096
#define QSTR 264   // x/y/q/k row stride (ushorts): 528B rows, 16B-aligned, 2-way-bank free
#define PSTR 72    // p8 row stride: 144B rows, 16B-aligned
#define VSTR 72    // v_t row stride

// workspace byte offsets
#define WS_WQT 0         // ushort wqT[768][256]   = 393216 B
#define WS_WOT 393216    // ushort woT[256][256]   = 131072 B
#define WS_BIAS 524288   // float biasf[8][16][256] = 524288 B

__device__ __forceinline__ unsigned short f2bf(float f) {
  unsigned u = __float_as_uint(f);
  return (unsigned short)((u + 0x7fffu + ((u >> 16) & 1u)) >> 16);
}
__device__ __forceinline__ unsigned packbf(float a, float b) {
  return (unsigned)f2bf(a) | ((unsigned)f2bf(b) << 16);
}
__device__ __forceinline__ float bflo(unsigned u) { return __uint_as_float(u << 16); }
__device__ __forceinline__ float bfhi(unsigned u) { return __uint_as_float(u & 0xffff0000u); }

// ---------------- kernel 1: weight transpose->bf16 + frag-ordered bias table ----------------
__global__ void prep_kernel(const float* __restrict__ w_qkv,
                            const float* __restrict__ w_out,
                            const float* __restrict__ rel,
                            unsigned short* __restrict__ wqT,
                            unsigned short* __restrict__ woT,
                            float* __restrict__ biasf) {
  const int stride = gridDim.x * blockDim.x;
  const int gid = blockIdx.x * blockDim.x + threadIdx.x;
  for (int e = gid; e < 256 * 768; e += stride) {     // wqT[c][k] = w_qkv[k][c]
    int k = e / 768, c = e - k * 768;
    wqT[c * 256 + k] = f2bf(w_qkv[e]);
  }
  for (int e = gid; e < 256 * 256; e += stride) {     // woT[c][k] = w_out[k][c]
    int k = e >> 8, c = e & 255;
    woT[c * 256 + k] = f2bf(w_out[e]);
  }
  // biasf[h][tile(mt*4+nt)][lane*4+reg] = rel bias for (i,j); -1e30 pad for j>=49
  for (int e = gid; e < 8 * 16 * 256; e += stride) {
    int h = e >> 12;
    int rem = e & 4095;
    int t = rem >> 8, l = (rem >> 2) & 63, rg = rem & 3;
    int i = (t >> 2) * 16 + ((l >> 4) << 2) + rg;
    int j = ((t & 3) << 4) + (l & 15);
    float v;
    if (j >= NTOK) v = -1e30f;
    else if (i >= NTOK) v = 0.f;
    else {
      int dh = i / 7 - j / 7 + 6;
      int dw = i % 7 - j % 7 + 6;
      v = rel[(dh * 13 + dw) * 8 + h];
    }
    biasf[e] = v;
  }
}

// ---------------- kernel 2: fused window attention via MFMA ----------------
struct SM {
  unsigned short xy[64 * QSTR];                    // 33792 B: x (bf16), later y
  union {
    struct { unsigned short q[64 * QSTR]; unsigned short k[64 * QSTR]; } qk;  // 67584
    unsigned short p8[8 * 64 * PSTR];                                          // 73728
  } u;
  unsigned short vt[256 * VSTR];                   // 36864 B: v transposed [d][token]
  unsigned short mkf[16 * 256];                    //  8192 B: mask, frag-ordered bf16
  float bq[768];
  float bo[256];
};                                                 // total 156672 B

__global__ void __launch_bounds__(512) winattn_mfma(
    const float* __restrict__ x,
    const float* __restrict__ mask,
    const float* __restrict__ b_qkv,
    const float* __restrict__ b_out,
    const unsigned short* __restrict__ wqT,
    const unsigned short* __restrict__ woT,
    const float* __restrict__ biasf,
    float* __restrict__ out)
{
  __shared__ SM sm;
  const int b = blockIdx.x;
  const int tid = threadIdx.x;
  const int lane = tid & 63;
  const int lo = lane & 15, hi = lane >> 4;
  const int w = tid >> 6;            // wave id = head id
  const f32x4 zf = {0.f, 0.f, 0.f, 0.f};

  // ---- phase 0: stage ----
  {
    const float4* xg = (const float4*)(x + (size_t)b * (NTOK * DIM));
    for (int e = tid; e < 49 * 64; e += 512) {
      float4 v = xg[e];
      int row = e >> 6, c4 = (e & 63) << 2;
      *(uint2*)&sm.xy[row * QSTR + c4] = make_uint2(packbf(v.x, v.y), packbf(v.z, v.w));
    }
    for (int e = tid; e < 15 * 66; e += 512) {     // zero token rows 49..63
      int row = 49 + e / 66, c = (e % 66) * 4;
      *(uint2*)&sm.xy[row * QSTR + c] = make_uint2(0u, 0u);
    }
    const float* mrow = mask + (size_t)(b & 63) * (NTOK * NTOK);
    for (int e = tid; e < 4096; e += 512) {        // frag-ordered mask (pad -> 0; -inf in biasf)
      int t = e >> 8, l = (e >> 2) & 63, rg = e & 3;
      int i = (t >> 2) * 16 + ((l >> 4) << 2) + rg;
      int j = ((t & 3) << 4) + (l & 15);
      float v = (i < NTOK && j < NTOK) ? mrow[i * NTOK + j] : 0.f;
      sm.mkf[e] = f2bf(v);
    }
    for (int e = tid; e < 768; e += 512) sm.bq[e] = b_qkv[e];
    if (tid < 256) sm.bo[tid] = b_out[tid];
  }
  __syncthreads();

  // ---- phase 1: QKV GEMM  D[c][r] = sum_k wT[c][k] x[r][k] ----
  {
    f32x4 acc[6][4];
    #pragma unroll
    for (int ct = 0; ct < 6; ++ct)
      #pragma unroll
      for (int rt = 0; rt < 4; ++rt) acc[ct][rt] = zf;
    #pragma unroll
    for (int ks = 0; ks < 8; ++ks) {
      short8 bx[4];
      #pragma unroll
      for (int rt = 0; rt < 4; ++rt)
        bx[rt] = *(const short8*)&sm.xy[(rt * 16 + lo) * QSTR + ks * 32 + hi * 8];
      #pragma unroll
      for (int ct = 0; ct < 6; ++ct) {
        const short8 af = *(const short8*)(wqT + (size_t)((w * 6 + ct) * 16 + lo) * 256 + ks * 32 + hi * 8);
        #pragma unroll
        for (int rt = 0; rt < 4; ++rt)
          acc[ct][rt] = __builtin_amdgcn_mfma_f32_16x16x32_bf16(af, bx[rt], acc[ct][rt], 0, 0, 0);
      }
    }
    #pragma unroll
    for (int ct = 0; ct < 6; ++ct) {
      const int ctg = w * 6 + ct;
      const int cb = ctg * 16 + hi * 4;
      f32x4 bias = *(const f32x4*)&sm.bq[cb];
      #pragma unroll
      for (int rt = 0; rt < 4; ++rt) {
        f32x4 v = acc[ct][rt] + bias;
        const int r = rt * 16 + lo;
        if (ctg < 16) {
          *(uint2*)&sm.u.qk.q[r * QSTR + cb] = make_uint2(packbf(v[0], v[1]), packbf(v[2], v[3]));
        } else if (ctg < 32) {
          *(uint2*)&sm.u.qk.k[r * QSTR + (cb - 256)] = make_uint2(packbf(v[0], v[1]), packbf(v[2], v[3]));
        } else {
          const int d = cb - 512;
          #pragma unroll
          for (int rg = 0; rg < 4; ++rg) sm.vt[(d + rg) * VSTR + r] = f2bf(v[rg]);
        }
      }
    }
  }
  __syncthreads();

  // ---- phase 2: S[i][j] = sum_d K[i][d] Q[j][d]  (wave = head) ----
  f32x4 s[4][4];
  {
    short8 ka[4], qa[4];
    #pragma unroll
    for (int m = 0; m < 4; ++m)
      ka[m] = *(const short8*)&sm.u.qk.k[(m * 16 + lo) * QSTR + w * 32 + hi * 8];
    #pragma unroll
    for (int n = 0; n < 4; ++n)
      qa[n] = *(const short8*)&sm.u.qk.q[(n * 16 + lo) * QSTR + w * 32 + hi * 8];
    #pragma unroll
    for (int m = 0; m < 4; ++m)
      #pragma unroll
      for (int n = 0; n < 4; ++n)
        s[m][n] = __builtin_amdgcn_mfma_f32_16x16x32_bf16(ka[m], qa[n], zf, 0, 0, 0);
  }
  __syncthreads();   // all QK^T reads done; q/k region becomes p8

  // ---- phase 3: softmax (no max-sub; |s| small), p -> bf16 LDS ----
  {
    const float* bfh = biasf + (w << 12);
    #pragma unroll
    for (int mt = 0; mt < 4; ++mt)
      #pragma unroll
      for (int nt = 0; nt < 4; ++nt) {
        const int t = mt * 4 + nt;
        f32x4 bm = *(const f32x4*)(bfh + t * 256 + lane * 4);
        uint2 mk = *(const uint2*)&sm.mkf[t * 256 + lane * 4];
        float mv0 = bflo(mk.x), mv1 = bfhi(mk.x), mv2 = bflo(mk.y), mv3 = bfhi(mk.y);
        float p0 = __expf(fmaf(s[mt][nt][0], 0.17677669529663687f, bm[0] + mv0));
        float p1 = __expf(fmaf(s[mt][nt][1], 0.17677669529663687f, bm[1] + mv1));
        float p2 = __expf(fmaf(s[mt][nt][2], 0.17677669529663687f, bm[2] + mv2));
        float p3 = __expf(fmaf(s[mt][nt][3], 0.17677669529663687f, bm[3] + mv3));
        const int ib = w * 64 + mt * 16 + hi * 4;
        sm.u.p8[(ib + 0) * PSTR + nt * 16 + lo] = f2bf(p0);
        sm.u.p8[(ib + 1) * PSTR + nt * 16 + lo] = f2bf(p1);
        sm.u.p8[(ib + 2) * PSTR + nt * 16 + lo] = f2bf(p2);
        sm.u.p8[(ib + 3) * PSTR + nt * 16 + lo] = f2bf(p3);
      }
  }
  // no barrier: p8[w] written and read only by wave w

  // ---- phase 4: PV  y[i][d] = sum_j p[i][j] v[j][d]; row-sum via ones-MFMA ----
  {
    short8 va[2][2];
    #pragma unroll
    for (int mt2 = 0; mt2 < 2; ++mt2)
      #pragma unroll
      for (int ks2 = 0; ks2 < 2; ++ks2)
        va[mt2][ks2] = *(const short8*)&sm.vt[(w * 32 + mt2 * 16 + lo) * VSTR + ks2 * 32 + hi * 8];
    short8 ones;
    #pragma unroll
    for (int q8 = 0; q8 < 8; ++q8) ones[q8] = (short)0x3F80;  // bf16 1.0
    f32x4 ya[2][4], ssum[4];
    #pragma unroll
    for (int nt = 0; nt < 4; ++nt) { ya[0][nt] = zf; ya[1][nt] = zf; ssum[nt] = zf; }
    #pragma unroll
    for (int nt = 0; nt < 4; ++nt)
      #pragma unroll
      for (int ks2 = 0; ks2 < 2; ++ks2) {
        short8 pb = *(const short8*)&sm.u.p8[(w * 64 + nt * 16 + lo) * PSTR + ks2 * 32 + hi * 8];
        ya[0][nt] = __builtin_amdgcn_mfma_f32_16x16x32_bf16(va[0][ks2], pb, ya[0][nt], 0, 0, 0);
        ya[1][nt] = __builtin_amdgcn_mfma_f32_16x16x32_bf16(va[1][ks2], pb, ya[1][nt], 0, 0, 0);
        ssum[nt] = __builtin_amdgcn_mfma_f32_16x16x32_bf16(ones, pb, ssum[nt], 0, 0, 0);
      }
    #pragma unroll
    for (int nt = 0; nt < 4; ++nt) {
      const float inv = 1.f / ssum[nt][0];
      const int r = nt * 16 + lo;
      #pragma unroll
      for (int mt2 = 0; mt2 < 2; ++mt2) {
        f32x4 v = ya[mt2][nt];
        *(uint2*)&sm.xy[r * QSTR + w * 32 + mt2 * 16 + hi * 4] =
            make_uint2(packbf(v[0] * inv, v[1] * inv), packbf(v[2] * inv, v[3] * inv));
      }
    }
  }
  __syncthreads();

  // ---- phase 5: proj  out[r][c] = sum_k y[r][k] woT[c][k] + bo[c] ----
  {
    f32x4 pacc[2][4];
    #pragma unroll
    for (int ct = 0; ct < 2; ++ct)
      #pragma unroll
      for (int rt = 0; rt < 4; ++rt) pacc[ct][rt] = zf;
    #pragma unroll
    for (int ks = 0; ks < 8; ++ks) {
      short8 yb[4];
      #pragma unroll
      for (int rt = 0; rt < 4; ++rt)
        yb[rt] = *(const short8*)&sm.xy[(rt * 16 + lo) * QSTR + ks * 32 + hi * 8];
      #pragma unroll
      for (int ct = 0; ct < 2; ++ct) {
        const short8 wf = *(const short8*)(woT + (size_t)((w * 2 + ct) * 16 + lo) * 256 + ks * 32 + hi * 8);
        #pragma unroll
        for (int rt = 0; rt < 4; ++rt)
          pacc[ct][rt] = __builtin_amdgcn_mfma_f32_16x16x32_bf16(wf, yb[rt], pacc[ct][rt], 0, 0, 0);
      }
    }
    float* og = out + (size_t)b * (NTOK * DIM);
    #pragma unroll
    for (int ct = 0; ct < 2; ++ct) {
      const int cb = (w * 2 + ct) * 16 + hi * 4;
      f32x4 bb = *(const f32x4*)&sm.bo[cb];
      #pragma unroll
      for (int rt = 0; rt < 4; ++rt) {
        const int r = rt * 16 + lo;
        if (r < NTOK) {
          f32x4 v = pacc[ct][rt] + bb;
          *(f32x4*)(og + (size_t)r * 256 + cb) = v;
        }
      }
    }
  }
}

extern "C" void kernel_launch(void* const* d_in, const int* in_sizes, int n_in,
                              void* d_out, int out_size, void* d_ws, size_t ws_size,
                              hipStream_t stream) {
  const float *x = nullptr, *mask = nullptr, *w_qkv = nullptr, *b_qkv = nullptr,
              *rel_t = nullptr, *w_out = nullptr, *b_out = nullptr;
  for (int i = 0; i < n_in; ++i) {
    const float* p = (const float*)d_in[i];
    switch (in_sizes[i]) {
      case 4096 * 49 * 256: x = p; break;
      case 64 * 49 * 49:    mask = p; break;
      case 256 * 768:       w_qkv = p; break;
      case 768:             b_qkv = p; break;
      case 169 * 8:         rel_t = p; break;
      case 256 * 256:       w_out = p; break;
      case 256:             b_out = p; break;
    }
  }
  char* wsb = (char*)d_ws;
  unsigned short* wqT = (unsigned short*)(wsb + WS_WQT);
  unsigned short* woT = (unsigned short*)(wsb + WS_WOT);
  float* biasf = (float*)(wsb + WS_BIAS);

  hipLaunchKernelGGL(prep_kernel, dim3(768), dim3(256), 0, stream,
                     w_qkv, w_out, rel_t, wqT, woT, biasf);
  hipLaunchKernelGGL(winattn_mfma, dim3(NBLK), dim3(512), 0, stream,
                     x, mask, b_qkv, b_out, wqT, woT, biasf, (float*)d_out);
}

// Round 6
// 346.429 us; speedup vs baseline: 10.4976x; 1.4275x over previous
//
#include <hip/hip_runtime.h>

typedef __attribute__((ext_vector_type(8))) short short8;
typedef __attribute__((ext_vector_type(4))) float f32x4;
typedef unsigned short u16;

#define NTOK 49
#define NBLK 4096

// shared pool offsets (u16 units)
#define XF  0       // x frags [rt4][ks8][64][8] = 16384 u16 (32KB); aliased by y frags [it4][h8][64][8]
#define QKP 16384   // per head 4096 u16: q[4][64][8] | k[4][64][8]; aliased by p[it4][ks2_2][64][8]
#define VTF 49152   // per head 2048 u16: [dblk2][ks2_2][64][8]
#define MKF 65536   // float[16][64][4] (8192 u16)
#define BQ  73728   // float[768] (1536 u16)
#define BO  75264   // float[256] (512 u16)
#define POOL 75776  // 151552 B

// workspace byte offsets
#define WS_WQT 0        // u16 wqTf[48][8][64][8] = 393216 B
#define WS_WOT 393216   // u16 woTf[16][8][64][8] = 131072 B
#define WS_BIAS 524288  // float biasf[8][16][64][4] = 131072 B

__device__ __forceinline__ u16 f2bf(float f) {
  unsigned u = __float_as_uint(f);
  return (u16)((u + 0x7fffu + ((u >> 16) & 1u)) >> 16);
}
__device__ __forceinline__ unsigned packbf(float a, float b) {
  return (unsigned)f2bf(a) | ((unsigned)f2bf(b) << 16);
}

// ---------------- prep: fragment-order weights (bf16) + bias table ----------------
__global__ void prep_kernel(const float* __restrict__ w_qkv,
                            const float* __restrict__ w_out,
                            const float* __restrict__ rel,
                            u16* __restrict__ wqTf,
                            u16* __restrict__ woTf,
                            float* __restrict__ biasf) {
  const int stride = gridDim.x * blockDim.x;
  const int gid = blockIdx.x * blockDim.x + threadIdx.x;
  // wqTf[ctg][ks][lane(lo,hi)][e] = w_qkv[ks*32+hi*8+e][ctg*16+lo]
  for (int e = gid; e < 48 * 8 * 64 * 8; e += stride) {
    int eL = e & 7, ln = (e >> 3) & 63, ks = (e >> 9) & 7, ctg = e >> 12;
    int k = ks * 32 + (ln >> 4) * 8 + eL;
    int c = ctg * 16 + (ln & 15);
    wqTf[e] = f2bf(w_qkv[k * 768 + c]);
  }
  for (int e = gid; e < 16 * 8 * 64 * 8; e += stride) {
    int eL = e & 7, ln = (e >> 3) & 63, ks = (e >> 9) & 7, ctg = e >> 12;
    int k = ks * 32 + (ln >> 4) * 8 + eL;
    int c = ctg * 16 + (ln & 15);
    woTf[e] = f2bf(w_out[k * 256 + c]);
  }
  // biasf[h][t=it*4+jt][lane][rg]: i = it*16+lo (col), j = jt*16+hi*4+rg (row of S^T)
  for (int e = gid; e < 8 * 16 * 64 * 4; e += stride) {
    int rg = e & 3, ln = (e >> 2) & 63, t = (e >> 8) & 15, h = e >> 12;
    int i = (t >> 2) * 16 + (ln & 15);
    int j = (t & 3) * 16 + (ln >> 4) * 4 + rg;
    float v;
    if (j >= NTOK) v = -1e30f;
    else if (i >= NTOK) v = 0.f;
    else {
      int dh = i / 7 - j / 7 + 6;
      int dw = i % 7 - j % 7 + 6;
      v = rel[(dh * 13 + dw) * 8 + h];
    }
    biasf[e] = v;
  }
}

// ---------------- fused window attention, fragment-ordered LDS ----------------
__global__ void __launch_bounds__(512, 2) winattn_mfma(
    const float* __restrict__ x,
    const float* __restrict__ mask,
    const float* __restrict__ b_qkv,
    const float* __restrict__ b_out,
    const u16* __restrict__ wqTf,
    const u16* __restrict__ woTf,
    const float* __restrict__ biasf,
    float* __restrict__ out)
{
  __shared__ u16 pool[POOL];
  const int b = blockIdx.x, tid = threadIdx.x;
  const int lane = tid & 63, lo = lane & 15, hi = lane >> 4;
  const int w = tid >> 6;                      // wave id = head id
  const f32x4 zf = {0.f, 0.f, 0.f, 0.f};
  float* mkf = (float*)(pool + MKF);
  float* bq  = (float*)(pool + BQ);
  float* bo  = (float*)(pool + BO);

  // ---- stage: x -> frag order; mask -> frag order; biases ----
  {
    const float4* xg = (const float4*)(x + (size_t)b * (NTOK * 256));
    for (int e = tid; e < 49 * 64; e += 512) {
      float4 v = xg[e];
      int r = e >> 6, c4 = (e & 63) << 2;
      int addr = (((r >> 4) * 8 + (c4 >> 5)) * 64 + ((c4 >> 3) & 3) * 16 + (r & 15)) * 8 + (c4 & 7);
      *(uint2*)&pool[XF + addr] = make_uint2(packbf(v.x, v.y), packbf(v.z, v.w));
    }
    for (int e = tid; e < 15 * 64; e += 512) {   // zero-pad tokens 49..63
      int r = 49 + (e >> 6), c4 = (e & 63) << 2;
      int addr = (((r >> 4) * 8 + (c4 >> 5)) * 64 + ((c4 >> 3) & 3) * 16 + (r & 15)) * 8 + (c4 & 7);
      *(uint2*)&pool[XF + addr] = make_uint2(0u, 0u);
    }
    const float* mrow = mask + (size_t)(b & 63) * (NTOK * NTOK);
    for (int e = tid; e < 4096; e += 512) {
      int rg = e & 3, l = (e >> 2) & 63, t = e >> 8;
      int i = (t >> 2) * 16 + (l & 15);
      int j = (t & 3) * 16 + (l >> 4) * 4 + rg;
      mkf[e] = (i < NTOK && j < NTOK) ? mrow[i * NTOK + j] : 0.f;
    }
    for (int e = tid; e < 768; e += 512) bq[e] = b_qkv[e];
    if (tid < 256) bo[tid] = b_out[tid];
  }
  __syncthreads();   // (a) xf/mkf/biases ready

  // ---- phase 1: QKV GEMM; wave w computes head w's q,k,v ----
  {
    const int ctg_[6] = {2*w, 2*w + 1, 16 + 2*w, 17 + 2*w, 32 + 2*w, 33 + 2*w};
    f32x4 acc[6][4];
    #pragma unroll
    for (int ct = 0; ct < 6; ++ct)
      #pragma unroll
      for (int rt = 0; rt < 4; ++rt) acc[ct][rt] = zf;
    #pragma unroll
    for (int ks = 0; ks < 8; ++ks) {
      short8 bx[4];
      #pragma unroll
      for (int rt = 0; rt < 4; ++rt)
        bx[rt] = *(const short8*)&pool[XF + ((rt * 8 + ks) * 64 + lane) * 8];
      #pragma unroll
      for (int ct = 0; ct < 6; ++ct) {
        short8 af = *(const short8*)&wqTf[((size_t)(ctg_[ct] * 8 + ks) * 64 + lane) * 8];
        #pragma unroll
        for (int rt = 0; rt < 4; ++rt)
          acc[ct][rt] = __builtin_amdgcn_mfma_f32_16x16x32_bf16(af, bx[rt], acc[ct][rt], 0, 0, 0);
      }
    }
    // epilogue: +bias, repack into frag-order LDS (all wave-local targets)
    #pragma unroll
    for (int ct = 0; ct < 6; ++ct) {
      const int ctg = ctg_[ct];
      f32x4 bias = *(const f32x4*)&bq[ctg * 16 + hi * 4];
      #pragma unroll
      for (int rt = 0; rt < 4; ++rt) {
        f32x4 v = acc[ct][rt] + bias;
        if (ct < 4) {          // q (ct 0,1) / k (ct 2,3): d = (ctg&1)*16 + hi*4 + rg
          int hi2 = (ctg & 1) * 2 + (hi >> 1);
          int eb = (hi & 1) * 4;
          int base = QKP + w * 4096 + (ct >= 2 ? 2048 : 0);
          *(uint2*)&pool[base + (rt * 64 + hi2 * 16 + lo) * 8 + eb] =
              make_uint2(packbf(v[0], v[1]), packbf(v[2], v[3]));
        } else {               // v: transpose scatter into vtf[dblk][ks2][lane'][e']
          int dblk = ctg & 1;
          int ks2 = rt >> 1;
          int hi2 = (rt & 1) * 2 + (lo >> 3);
          int e2 = lo & 7;
          int vb = VTF + w * 2048 + ((dblk * 2 + ks2) * 64 + hi2 * 16) * 8 + e2;
          pool[vb + (hi * 4 + 0) * 8] = f2bf(v[0]);
          pool[vb + (hi * 4 + 1) * 8] = f2bf(v[1]);
          pool[vb + (hi * 4 + 2) * 8] = f2bf(v[2]);
          pool[vb + (hi * 4 + 3) * 8] = f2bf(v[3]);
        }
      }
    }
  }
  __syncthreads();   // (b) all xf reads done -> yf may alias xf

  // ---- phase 2: S^T tiles = mfma(qa, ka); lane holds S[i=it*16+lo][j=jt*16+hi*4+rg] ----
  f32x4 sT[4][4];
  {
    short8 qa[4], ka[4];
    #pragma unroll
    for (int t2 = 0; t2 < 4; ++t2) {
      qa[t2] = *(const short8*)&pool[QKP + w * 4096 + (t2 * 64 + lane) * 8];
      ka[t2] = *(const short8*)&pool[QKP + w * 4096 + 2048 + (t2 * 64 + lane) * 8];
    }
    #pragma unroll
    for (int jt = 0; jt < 4; ++jt)
      #pragma unroll
      for (int it = 0; it < 4; ++it)
        sT[jt][it] = __builtin_amdgcn_mfma_f32_16x16x32_bf16(qa[jt], ka[it], zf, 0, 0, 0);
  }

  // ---- phase 3: softmax (no max-sub), p -> frag-order LDS (aliases q/k) ----
  float inv[4];
  {
    const float* bh = biasf + ((size_t)w << 12);
    float rs[4] = {0.f, 0.f, 0.f, 0.f};
    #pragma unroll
    for (int jt = 0; jt < 4; ++jt) {
      #pragma unroll
      for (int it = 0; it < 4; ++it) {
        const int t = it * 4 + jt;
        f32x4 bm = *(const f32x4*)&bh[(t * 64 + lane) * 4];
        f32x4 mm = *(const f32x4*)&mkf[(t * 64 + lane) * 4];
        float p0 = __expf(fmaf(sT[jt][it][0], 0.17677669529663687f, bm[0] + mm[0]));
        float p1 = __expf(fmaf(sT[jt][it][1], 0.17677669529663687f, bm[1] + mm[1]));
        float p2 = __expf(fmaf(sT[jt][it][2], 0.17677669529663687f, bm[2] + mm[2]));
        float p3 = __expf(fmaf(sT[jt][it][3], 0.17677669529663687f, bm[3] + mm[3]));
        rs[it] += (p0 + p1) + (p2 + p3);
        int hi2 = (jt & 1) * 2 + (hi >> 1);
        int eb = (hi & 1) * 4;
        *(uint2*)&pool[QKP + w * 4096 + ((it * 2 + (jt >> 1)) * 64 + hi2 * 16 + lo) * 8 + eb] =
            make_uint2(packbf(p0, p1), packbf(p2, p3));
      }
    }
    #pragma unroll
    for (int it = 0; it < 4; ++it) {
      float r2 = rs[it] + __shfl_xor(rs[it], 16);
      float r4 = r2 + __shfl_xor(r2, 32);
      inv[it] = 1.f / r4;
    }
  }

  // ---- phase 4: PV; y frags -> LDS (aliases xf) ----
  {
    short8 va[2][2];
    #pragma unroll
    for (int dblk = 0; dblk < 2; ++dblk)
      #pragma unroll
      for (int k2 = 0; k2 < 2; ++k2)
        va[dblk][k2] = *(const short8*)&pool[VTF + w * 2048 + ((dblk * 2 + k2) * 64 + lane) * 8];
    f32x4 ya[2][4];
    #pragma unroll
    for (int it = 0; it < 4; ++it) { ya[0][it] = zf; ya[1][it] = zf; }
    #pragma unroll
    for (int it = 0; it < 4; ++it)
      #pragma unroll
      for (int k2 = 0; k2 < 2; ++k2) {
        short8 pb = *(const short8*)&pool[QKP + w * 4096 + ((it * 2 + k2) * 64 + lane) * 8];
        ya[0][it] = __builtin_amdgcn_mfma_f32_16x16x32_bf16(va[0][k2], pb, ya[0][it], 0, 0, 0);
        ya[1][it] = __builtin_amdgcn_mfma_f32_16x16x32_bf16(va[1][k2], pb, ya[1][it], 0, 0, 0);
      }
    #pragma unroll
    for (int it = 0; it < 4; ++it) {
      #pragma unroll
      for (int dblk = 0; dblk < 2; ++dblk) {
        float y0 = ya[dblk][it][0] * inv[it];
        float y1 = ya[dblk][it][1] * inv[it];
        float y2 = ya[dblk][it][2] * inv[it];
        float y3 = ya[dblk][it][3] * inv[it];
        int hi2 = dblk * 2 + (hi >> 1);
        int eb = (hi & 1) * 4;
        *(uint2*)&pool[XF + ((it * 8 + w) * 64 + hi2 * 16 + lo) * 8 + eb] =
            make_uint2(packbf(y0, y1), packbf(y2, y3));
      }
    }
  }
  __syncthreads();   // (c) y frags ready for all waves

  // ---- phase 5: output projection ----
  {
    f32x4 pacc[2][4];
    #pragma unroll
    for (int ct = 0; ct < 2; ++ct)
      #pragma unroll
      for (int rt = 0; rt < 4; ++rt) pacc[ct][rt] = zf;
    #pragma unroll
    for (int ks = 0; ks < 8; ++ks) {
      short8 yb[4];
      #pragma unroll
      for (int rt = 0; rt < 4; ++rt)
        yb[rt] = *(const short8*)&pool[XF + ((rt * 8 + ks) * 64 + lane) * 8];
      #pragma unroll
      for (int ct = 0; ct < 2; ++ct) {
        short8 wf = *(const short8*)&woTf[((size_t)((w * 2 + ct) * 8 + ks) * 64 + lane) * 8];
        #pragma unroll
        for (int rt = 0; rt < 4; ++rt)
          pacc[ct][rt] = __builtin_amdgcn_mfma_f32_16x16x32_bf16(wf, yb[rt], pacc[ct][rt], 0, 0, 0);
      }
    }
    float* og = out + (size_t)b * (NTOK * 256);
    #pragma unroll
    for (int ct = 0; ct < 2; ++ct) {
      const int cb = (w * 2 + ct) * 16 + hi * 4;
      f32x4 bb = *(const f32x4*)&bo[cb];
      #pragma unroll
      for (int rt = 0; rt < 4; ++rt) {
        const int r = rt * 16 + lo;
        if (r < NTOK) {
          f32x4 vv = pacc[ct][rt] + bb;
          *(f32x4*)(og + (size_t)r * 256 + cb) = vv;
        }
      }
    }
  }
}

extern "C" void kernel_launch(void* const* d_in, const int* in_sizes, int n_in,
                              void* d_out, int out_size, void* d_ws, size_t ws_size,
                              hipStream_t stream) {
  const float *x = nullptr, *mask = nullptr, *w_qkv = nullptr, *b_qkv = nullptr,
              *rel_t = nullptr, *w_out = nullptr, *b_out = nullptr;
  for (int i = 0; i < n_in; ++i) {
    const float* p = (const float*)d_in[i];
    switch (in_sizes[i]) {
      case 4096 * 49 * 256: x = p; break;
      case 64 * 49 * 49:    mask = p; break;
      case 256 * 768:       w_qkv = p; break;
      case 768:             b_qkv = p; break;
      case 169 * 8:         rel_t = p; break;
      case 256 * 256:       w_out = p; break;
      case 256:             b_out = p; break;
    }
  }
  char* wsb = (char*)d_ws;
  u16* wqTf = (u16*)(wsb + WS_WQT);
  u16* woTf = (u16*)(wsb + WS_WOT);
  float* biasf = (float*)(wsb + WS_BIAS);

  hipLaunchKernelGGL(prep_kernel, dim3(512), dim3(256), 0, stream,
                     w_qkv, w_out, rel_t, wqTf, woTf, biasf);
  hipLaunchKernelGGL(winattn_mfma, dim3(NBLK), dim3(512), 0, stream,
                     x, mask, b_qkv, b_out, wqTf, woTf, biasf, (float*)d_out);
}

// Round 7
// 289.973 us; speedup vs baseline: 12.5415x; 1.1947x over previous
//
#include <hip/hip_runtime.h>

typedef __attribute__((ext_vector_type(8))) short short8;
typedef __attribute__((ext_vector_type(4))) float f32x4;
typedef unsigned short u16;

#define NTOK 49
#define NBLK 4096

// shared pool offsets (u16 units)
#define XF  0       // x frags [rt4][ks8][64][8] = 16384 u16 (32KB); later y frags [it4][h8][64][8]
#define QKP 16384   // per head 4096 u16: q[4][64][8] | k[4][64][8]  (write ph1, read ph2 only)
#define VTF 49152   // per head 2048 u16: v^T [dblk2][k2_2][64][8]
#define MKF 65536   // float[16][64][4] mask frags (8192 u16)
#define BQ  73728   // float[768]
#define BO  75264   // float[256]
#define POOL 75776  // 151552 B

// workspace byte offsets
#define WS_WQT 0        // u16 wqTf[48][8][64][8] = 393216 B
#define WS_WOT 393216   // u16 woTf[16][8][64][8] = 131072 B
#define WS_BIAS 524288  // float biasf[8][16][64][4] = 131072 B

__device__ __forceinline__ u16 f2bf(float f) {
  unsigned u = __float_as_uint(f);
  return (u16)((u + 0x7fffu + ((u >> 16) & 1u)) >> 16);
}
__device__ __forceinline__ unsigned packbf(float a, float b) {
  return (unsigned)f2bf(a) | ((unsigned)f2bf(b) << 16);
}

// ---------------- prep: fragment-order weights (bf16) + bias table ----------------
__global__ void prep_kernel(const float* __restrict__ w_qkv,
                            const float* __restrict__ w_out,
                            const float* __restrict__ rel,
                            u16* __restrict__ wqTf,
                            u16* __restrict__ woTf,
                            float* __restrict__ biasf) {
  const int stride = gridDim.x * blockDim.x;
  const int gid = blockIdx.x * blockDim.x + threadIdx.x;
  for (int e = gid; e < 48 * 8 * 64 * 8; e += stride) {
    int eL = e & 7, ln = (e >> 3) & 63, ks = (e >> 9) & 7, ctg = e >> 12;
    int k = ks * 32 + (ln >> 4) * 8 + eL;
    int c = ctg * 16 + (ln & 15);
    wqTf[e] = f2bf(w_qkv[k * 768 + c]);
  }
  for (int e = gid; e < 16 * 8 * 64 * 8; e += stride) {
    int eL = e & 7, ln = (e >> 3) & 63, ks = (e >> 9) & 7, ctg = e >> 12;
    int k = ks * 32 + (ln >> 4) * 8 + eL;
    int c = ctg * 16 + (ln & 15);
    woTf[e] = f2bf(w_out[k * 256 + c]);
  }
  // biasf[h][t=it*4+jt][lane][rg]: i = it*16+lo, j = jt*16+hi*4+rg
  for (int e = gid; e < 8 * 16 * 64 * 4; e += stride) {
    int rg = e & 3, ln = (e >> 2) & 63, t = (e >> 8) & 15, hh = e >> 12;
    int i = (t >> 2) * 16 + (ln & 15);
    int j = (t & 3) * 16 + (ln >> 4) * 4 + rg;
    float v;
    if (j >= NTOK) v = -1e30f;
    else if (i >= NTOK) v = 0.f;
    else {
      int dh = i / 7 - j / 7 + 6;
      int dw = i % 7 - j % 7 + 6;
      v = rel[(dh * 13 + dw) * 8 + hh];
    }
    biasf[e] = v;
  }
}

// ---------------- fused window attention, 16 waves ----------------
__global__ void __launch_bounds__(1024, 4) winattn_mfma(
    const float* __restrict__ x,
    const float* __restrict__ mask,
    const float* __restrict__ b_qkv,
    const float* __restrict__ b_out,
    const u16* __restrict__ wqTf,
    const u16* __restrict__ woTf,
    const float* __restrict__ biasf,
    float* __restrict__ out)
{
  __shared__ u16 pool[POOL];
  const int b = blockIdx.x, tid = threadIdx.x;
  const int lane = tid & 63, lo = lane & 15, hi = lane >> 4;
  const int w = tid >> 6;            // 0..15
  const int h = w & 7;               // head
  const int it0 = (w >> 3) * 2;      // i-tile base: 0 or 2
  const f32x4 zf = {0.f, 0.f, 0.f, 0.f};
  float* mkf = (float*)(pool + MKF);
  float* bq  = (float*)(pool + BQ);
  float* bo  = (float*)(pool + BO);

  // ---- stage ----
  {
    const float4* xg = (const float4*)(x + (size_t)b * (NTOK * 256));
    for (int e = tid; e < 49 * 64; e += 1024) {
      float4 v = xg[e];
      int r = e >> 6, c4 = (e & 63) << 2;
      int addr = (((r >> 4) * 8 + (c4 >> 5)) * 64 + ((c4 >> 3) & 3) * 16 + (r & 15)) * 8 + (c4 & 7);
      *(uint2*)&pool[XF + addr] = make_uint2(packbf(v.x, v.y), packbf(v.z, v.w));
    }
    if (tid < 15 * 64) {   // zero-pad tokens 49..63
      int e = tid;
      int r = 49 + (e >> 6), c4 = (e & 63) << 2;
      int addr = (((r >> 4) * 8 + (c4 >> 5)) * 64 + ((c4 >> 3) & 3) * 16 + (r & 15)) * 8 + (c4 & 7);
      *(uint2*)&pool[XF + addr] = make_uint2(0u, 0u);
    }
    const float* mrow = mask + (size_t)(b & 63) * (NTOK * NTOK);
    for (int e = tid; e < 4096; e += 1024) {
      int rg = e & 3, l = (e >> 2) & 63, t = e >> 8;
      int i = (t >> 2) * 16 + (l & 15);
      int j = (t & 3) * 16 + (l >> 4) * 4 + rg;
      mkf[e] = (i < NTOK && j < NTOK) ? mrow[i * NTOK + j] : 0.f;
    }
    if (tid < 768) bq[tid] = b_qkv[tid];
    if (tid < 256) bo[tid] = b_out[tid];
  }
  __syncthreads();   // (a)

  // ---- phase 1: QKV GEMM, 3 ctg tiles per wave ----
  {
    f32x4 acc[3][4];
    #pragma unroll
    for (int ct = 0; ct < 3; ++ct)
      #pragma unroll
      for (int rt = 0; rt < 4; ++rt) acc[ct][rt] = zf;
    #pragma unroll
    for (int ks = 0; ks < 8; ++ks) {
      short8 bx[4];
      #pragma unroll
      for (int rt = 0; rt < 4; ++rt)
        bx[rt] = *(const short8*)&pool[XF + ((rt * 8 + ks) * 64 + lane) * 8];
      #pragma unroll
      for (int ct = 0; ct < 3; ++ct) {
        short8 af = *(const short8*)&wqTf[((size_t)((3 * w + ct) * 8 + ks) * 64 + lane) * 8];
        #pragma unroll
        for (int rt = 0; rt < 4; ++rt)
          acc[ct][rt] = __builtin_amdgcn_mfma_f32_16x16x32_bf16(af, bx[rt], acc[ct][rt], 0, 0, 0);
      }
    }
    #pragma unroll
    for (int ct = 0; ct < 3; ++ct) {
      const int ctg = 3 * w + ct;
      const int head2 = (ctg & 15) >> 1;
      f32x4 bias = *(const f32x4*)&bq[ctg * 16 + hi * 4];
      #pragma unroll
      for (int rt = 0; rt < 4; ++rt) {
        f32x4 v = acc[ct][rt] + bias;
        if (ctg < 32) {        // q or k
          int base = QKP + head2 * 4096 + (ctg >= 16 ? 2048 : 0);
          int hi2 = (ctg & 1) * 2 + (hi >> 1);
          int eb = (hi & 1) * 4;
          *(uint2*)&pool[base + (rt * 64 + hi2 * 16 + lo) * 8 + eb] =
              make_uint2(packbf(v[0], v[1]), packbf(v[2], v[3]));
        } else {               // v: transpose scatter
          int dblk = ctg & 1;
          int ks2 = rt >> 1;
          int hi2 = (rt & 1) * 2 + (lo >> 3);
          int e2 = lo & 7;
          int vb = VTF + head2 * 2048 + ((dblk * 2 + ks2) * 64 + hi2 * 16) * 8 + e2;
          pool[vb + (hi * 4 + 0) * 8] = f2bf(v[0]);
          pool[vb + (hi * 4 + 1) * 8] = f2bf(v[1]);
          pool[vb + (hi * 4 + 2) * 8] = f2bf(v[2]);
          pool[vb + (hi * 4 + 3) * 8] = f2bf(v[3]);
        }
      }
    }
  }
  __syncthreads();   // (b)  q/k/v visible to all; XF dead (y may overwrite)

  // ---- phase 2+3: S^T tiles (it0..it0+1) + softmax; p stays in registers ----
  float rs0 = 0.f, rs1 = 0.f;
  unsigned pkp[4][2][2];   // [jt][itL][pair]  (static indexing only)
  {
    short8 ka0 = *(const short8*)&pool[QKP + h * 4096 + 2048 + ((it0 + 0) * 64 + lane) * 8];
    short8 ka1 = *(const short8*)&pool[QKP + h * 4096 + 2048 + ((it0 + 1) * 64 + lane) * 8];
    const float* bh = biasf + ((size_t)h << 12);
    #pragma unroll
    for (int jt = 0; jt < 4; ++jt) {
      short8 qa = *(const short8*)&pool[QKP + h * 4096 + (jt * 64 + lane) * 8];
      f32x4 s0 = __builtin_amdgcn_mfma_f32_16x16x32_bf16(qa, ka0, zf, 0, 0, 0);
      f32x4 s1 = __builtin_amdgcn_mfma_f32_16x16x32_bf16(qa, ka1, zf, 0, 0, 0);
      {
        const int t = (it0 + 0) * 4 + jt;
        f32x4 bm = *(const f32x4*)&bh[(t * 64 + lane) * 4];
        f32x4 mm = *(const f32x4*)&mkf[(t * 64 + lane) * 4];
        float p0 = __expf(fmaf(s0[0], 0.17677669529663687f, bm[0] + mm[0]));
        float p1 = __expf(fmaf(s0[1], 0.17677669529663687f, bm[1] + mm[1]));
        float p2 = __expf(fmaf(s0[2], 0.17677669529663687f, bm[2] + mm[2]));
        float p3 = __expf(fmaf(s0[3], 0.17677669529663687f, bm[3] + mm[3]));
        rs0 += (p0 + p1) + (p2 + p3);
        pkp[jt][0][0] = packbf(p0, p1);
        pkp[jt][0][1] = packbf(p2, p3);
      }
      {
        const int t = (it0 + 1) * 4 + jt;
        f32x4 bm = *(const f32x4*)&bh[(t * 64 + lane) * 4];
        f32x4 mm = *(const f32x4*)&mkf[(t * 64 + lane) * 4];
        float p0 = __expf(fmaf(s1[0], 0.17677669529663687f, bm[0] + mm[0]));
        float p1 = __expf(fmaf(s1[1], 0.17677669529663687f, bm[1] + mm[1]));
        float p2 = __expf(fmaf(s1[2], 0.17677669529663687f, bm[2] + mm[2]));
        float p3 = __expf(fmaf(s1[3], 0.17677669529663687f, bm[3] + mm[3]));
        rs1 += (p0 + p1) + (p2 + p3);
        pkp[jt][1][0] = packbf(p0, p1);
        pkp[jt][1][1] = packbf(p2, p3);
      }
    }
  }
  float inv0, inv1;
  {
    float r2 = rs0 + __shfl_xor(rs0, 16);
    inv0 = 1.f / (r2 + __shfl_xor(r2, 32));
    float r3 = rs1 + __shfl_xor(rs1, 16);
    inv1 = 1.f / (r3 + __shfl_xor(r3, 32));
  }

  // ---- phase 4: PV; pb assembled via shfl from pkp ----
  {
    short8 va[2][2];
    #pragma unroll
    for (int dblk = 0; dblk < 2; ++dblk)
      #pragma unroll
      for (int k2 = 0; k2 < 2; ++k2)
        va[dblk][k2] = *(const short8*)&pool[VTF + h * 2048 + ((dblk * 2 + k2) * 64 + lane) * 8];
    f32x4 ya[2][2];
    ya[0][0] = zf; ya[0][1] = zf; ya[1][0] = zf; ya[1][1] = zf;
    const int src0 = lo + ((hi & 1) * 2) * 16;
    const int src1 = src0 + 16;
    const bool hiSel = (hi & 2) != 0;
    #pragma unroll
    for (int itL = 0; itL < 2; ++itL)
      #pragma unroll
      for (int k2 = 0; k2 < 2; ++k2) {
        unsigned a0 = (unsigned)__shfl((int)pkp[2 * k2][itL][0], src0);
        unsigned b0 = (unsigned)__shfl((int)pkp[2 * k2 + 1][itL][0], src0);
        unsigned a1 = (unsigned)__shfl((int)pkp[2 * k2][itL][1], src0);
        unsigned b1 = (unsigned)__shfl((int)pkp[2 * k2 + 1][itL][1], src0);
        unsigned a2 = (unsigned)__shfl((int)pkp[2 * k2][itL][0], src1);
        unsigned b2 = (unsigned)__shfl((int)pkp[2 * k2 + 1][itL][0], src1);
        unsigned a3 = (unsigned)__shfl((int)pkp[2 * k2][itL][1], src1);
        unsigned b3 = (unsigned)__shfl((int)pkp[2 * k2 + 1][itL][1], src1);
        union { unsigned u[4]; short8 s8; } pb;
        pb.u[0] = hiSel ? b0 : a0;
        pb.u[1] = hiSel ? b1 : a1;
        pb.u[2] = hiSel ? b2 : a2;
        pb.u[3] = hiSel ? b3 : a3;
        ya[0][itL] = __builtin_amdgcn_mfma_f32_16x16x32_bf16(va[0][k2], pb.s8, ya[0][itL], 0, 0, 0);
        ya[1][itL] = __builtin_amdgcn_mfma_f32_16x16x32_bf16(va[1][k2], pb.s8, ya[1][itL], 0, 0, 0);
      }
    #pragma unroll
    for (int itL = 0; itL < 2; ++itL) {
      const float inv = itL ? inv1 : inv0;
      #pragma unroll
      for (int dblk = 0; dblk < 2; ++dblk) {
        float y0 = ya[dblk][itL][0] * inv;
        float y1 = ya[dblk][itL][1] * inv;
        float y2 = ya[dblk][itL][2] * inv;
        float y3 = ya[dblk][itL][3] * inv;
        int hi2 = dblk * 2 + (hi >> 1);
        int eb = (hi & 1) * 4;
        *(uint2*)&pool[XF + (((it0 + itL) * 8 + h) * 64 + hi2 * 16 + lo) * 8 + eb] =
            make_uint2(packbf(y0, y1), packbf(y2, y3));
      }
    }
  }
  __syncthreads();   // (c)

  // ---- phase 5: output projection, 1 ctg per wave ----
  {
    f32x4 pacc[4];
    pacc[0] = zf; pacc[1] = zf; pacc[2] = zf; pacc[3] = zf;
    #pragma unroll
    for (int ks = 0; ks < 8; ++ks) {
      short8 wf = *(const short8*)&woTf[((size_t)(w * 8 + ks) * 64 + lane) * 8];
      #pragma unroll
      for (int rt = 0; rt < 4; ++rt) {
        short8 yb = *(const short8*)&pool[XF + ((rt * 8 + ks) * 64 + lane) * 8];
        pacc[rt] = __builtin_amdgcn_mfma_f32_16x16x32_bf16(wf, yb, pacc[rt], 0, 0, 0);
      }
    }
    float* og = out + (size_t)b * (NTOK * 256);
    const int cb = w * 16 + hi * 4;
    f32x4 bb = *(const f32x4*)&bo[cb];
    #pragma unroll
    for (int rt = 0; rt < 4; ++rt) {
      const int r = rt * 16 + lo;
      if (r < NTOK) {
        f32x4 vv = pacc[rt] + bb;
        *(f32x4*)(og + (size_t)r * 256 + cb) = vv;
      }
    }
  }
}

extern "C" void kernel_launch(void* const* d_in, const int* in_sizes, int n_in,
                              void* d_out, int out_size, void* d_ws, size_t ws_size,
                              hipStream_t stream) {
  const float *x = nullptr, *mask = nullptr, *w_qkv = nullptr, *b_qkv = nullptr,
              *rel_t = nullptr, *w_out = nullptr, *b_out = nullptr;
  for (int i = 0; i < n_in; ++i) {
    const float* p = (const float*)d_in[i];
    switch (in_sizes[i]) {
      case 4096 * 49 * 256: x = p; break;
      case 64 * 49 * 49:    mask = p; break;
      case 256 * 768:       w_qkv = p; break;
      case 768:             b_qkv = p; break;
      case 169 * 8:         rel_t = p; break;
      case 256 * 256:       w_out = p; break;
      case 256:             b_out = p; break;
    }
  }
  char* wsb = (char*)d_ws;
  u16* wqTf = (u16*)(wsb + WS_WQT);
  u16* woTf = (u16*)(wsb + WS_WOT);
  float* biasf = (float*)(wsb + WS_BIAS);

  hipLaunchKernelGGL(prep_kernel, dim3(512), dim3(256), 0, stream,
                     w_qkv, w_out, rel_t, wqTf, woTf, biasf);
  hipLaunchKernelGGL(winattn_mfma, dim3(NBLK), dim3(1024), 0, stream,
                     x, mask, b_qkv, b_out, wqTf, woTf, biasf, (float*)d_out);
}